// Round 7
// baseline (180.711 us; speedup 1.0000x reference)
//
#include <hip/hip_runtime.h>
#include <hip/hip_bf16.h>

typedef __attribute__((ext_vector_type(8))) unsigned short u16x8;
typedef __attribute__((ext_vector_type(4))) unsigned short u16x4;
typedef __attribute__((ext_vector_type(8))) short short8;
typedef __attribute__((ext_vector_type(4))) float floatx4;

#define BS 64
#define CIN 256
#define II 1024
#define OO 320
#define JJ 10
#define DD 32

__device__ __forceinline__ float b2f(unsigned short u) {
    union { unsigned int i; float f; } x; x.i = ((unsigned int)u) << 16; return x.f;
}
__device__ __forceinline__ unsigned short f2b(float f) {
    union { float f; unsigned int i; } x; x.f = f;
    unsigned int r = x.i + 0x7fffu + ((x.i >> 16) & 1u);
    return (unsigned short)(r >> 16);
}
// sum over the 16 lm-lanes (i dimension within a frag)
__device__ __forceinline__ float redlm(float v) {
    v += __shfl_xor(v, 1); v += __shfl_xor(v, 2);
    v += __shfl_xor(v, 4); v += __shfl_xor(v, 8);
    return v;
}

// ---------- prep: W f32 [320][256] -> chunk-major frag-linear bf16 Wl ----------
// gid = (((oc*8 + ks)*4 + mtl)*4 + quad)*16 + lm ; group holds 8 bf16:
//   W[o = oc*64 + mtl*16 + lm][c = ks*32 + quad*8 + j], j=0..7
__global__ __launch_bounds__(256) void k_prepW(const float* __restrict__ W,
                                               unsigned short* __restrict__ Wl) {
    int gid = blockIdx.x * 256 + threadIdx.x;   // 40 blocks -> 10240
    int lm = gid & 15;
    int quad = (gid >> 4) & 3;
    int mtl = (gid >> 6) & 3;
    int ks = (gid >> 8) & 7;
    int oc = gid >> 11;
    const float* src = W + (size_t)(oc * 64 + mtl * 16 + lm) * CIN + ks * 32 + quad * 8;
    float4 v0 = *(const float4*)src;
    float4 v1 = *(const float4*)(src + 4);
    u16x8 u;
    u[0] = f2b(v0.x); u[1] = f2b(v0.y); u[2] = f2b(v0.z); u[3] = f2b(v0.w);
    u[4] = f2b(v1.x); u[5] = f2b(v1.y); u[6] = f2b(v1.z); u[7] = f2b(v1.w);
    *(u16x8*)(Wl + (size_t)gid * 8) = u;
}

// ---------- K1: GEMM (direct-from-x B-frags) + fused rowsum partials ----------
// grid (8 ic, 64 b) x 512 thr (8 waves). Wave w owns i = ic*128 + w*16 + lm.
// 5 o-chunks of 64; acc lives only within a chunk (16 VGPR).
// __launch_bounds__(512,2): cap 256 VGPR so the 64 x-loads can stay in flight (R6: VGPR=48 strangled MLP).
__global__ __launch_bounds__(512, 2) void k_gemm3(const float* __restrict__ x,
                                                  const unsigned short* __restrict__ Wl,
                                                  const float* __restrict__ Wb,
                                                  unsigned short* __restrict__ pred,
                                                  float* __restrict__ psum0) {
    __shared__ unsigned short AsF[2048 * 8];   // 32 KB: one o-chunk frag-linear
    __shared__ unsigned short CT[64 * 132];    // 16.9 KB: epilogue transpose tile (stride 132: quads on disjoint banks)
    __shared__ float ws_lds[8][OO];            // 10 KB
    __shared__ float Wb_lds[OO];

    const int ic = blockIdx.x, b = blockIdx.y;
    const int t = threadIdx.x, w = t >> 6, l = t & 63;
    const int lm = l & 15, quad = l >> 4;

    if (t < OO) Wb_lds[t] = Wb[t];

    // ---- issue ALL 64 x-loads (read-once from HBM), then convert to B-frags ----
    const float* xb = x + (size_t)b * CIN * II + ic * 128 + w * 16 + lm;
    float rx[64];
#pragma unroll
    for (int ks = 0; ks < 8; ++ks)
#pragma unroll
        for (int j = 0; j < 8; ++j)
            rx[ks * 8 + j] = xb[(size_t)(ks * 32 + quad * 8 + j) * II];

    short8 bfrag[8];
#pragma unroll
    for (int ks = 0; ks < 8; ++ks) {
        short8 f;
#pragma unroll
        for (int j = 0; j < 8; ++j) f[j] = (short)f2b(rx[ks * 8 + j]);
        bfrag[ks] = f;
    }

#pragma unroll 1
    for (int oc = 0; oc < 5; ++oc) {
        __syncthreads();   // prior chunk done reading AsF / CT
        {
            const u16x8* src = (const u16x8*)Wl + oc * 2048;
            u16x8* dst = (u16x8*)AsF;
            for (int u = t; u < 2048; u += 512) dst[u] = src[u];
        }
        __syncthreads();

        floatx4 acc[4] = {};
#pragma unroll
        for (int ks = 0; ks < 8; ++ks)
#pragma unroll
            for (int mtl = 0; mtl < 4; ++mtl) {
                short8 af = *(const short8*)(AsF + (size_t)(((ks * 4 + mtl) * 4 + quad) * 16 + lm) * 8);
                acc[mtl] = __builtin_amdgcn_mfma_f32_16x16x32_bf16(af, bfrag[ks], acc[mtl], 0, 0, 0);
            }

        // epilogue: o_l = mtl*16 + quad*4 + r ; i_local = w*16 + lm
#pragma unroll
        for (int mtl = 0; mtl < 4; ++mtl)
#pragma unroll
            for (int r = 0; r < 4; ++r) {
                int o_l = mtl * 16 + quad * 4 + r;
                float v = acc[mtl][r] + Wb_lds[oc * 64 + o_l];
                CT[o_l * 132 + w * 16 + lm] = f2b(v);
                float rs = redlm(v);
                if (lm == 0) ws_lds[w][oc * 64 + o_l] = rs;
            }
        __syncthreads();

        // cooperative vectorized store: 4 passes x 16 rows, 32 thr/row x u16x4
        {
            int r = t >> 5, col = (t & 31) * 4;
            unsigned short* pbase = pred + ((size_t)b * OO + oc * 64) * II + ic * 128 + col;
#pragma unroll
            for (int p = 0; p < 4; ++p) {
                int row = p * 16 + r;
                u16x4 vv = *(const u16x4*)&CT[row * 132 + col];
                *(u16x4*)(pbase + (size_t)row * II) = vv;
            }
        }
    }
    __syncthreads();
    for (int u = t; u < OO; u += 512) {
        float s = 0.f;
#pragma unroll
        for (int ww = 0; ww < 8; ++ww) s += ws_lds[ww][u];
        psum0[((size_t)ic * BS + b) * OO + u] = s;
    }
}

// ---------- routing pass: consume psumIn -> squash -> delta -> softmax -> wsum partials ----------
// grid (4 ic, 64 b) x 640 thr (10 waves, one per j); ic slice = 256 i.
template <bool FIRST>
__global__ __launch_bounds__(640) void k_routeP(const float* __restrict__ psumIn, int nslice, float scale,
                                                const unsigned short* __restrict__ pred,
                                                float* __restrict__ blogG,
                                                float* __restrict__ psumOut) {
    __shared__ float s_lds[OO];
    __shared__ float v_lds[OO];
    __shared__ float cf[JJ];
    __shared__ float dbuf[JJ][256];

    const int ic = blockIdx.x, b = blockIdx.y;
    const int t = threadIdx.x, w = t >> 6, l = t & 63;

    if (t < OO) {
        float s = 0.f;
        for (int sl = 0; sl < nslice; ++sl) s += psumIn[((size_t)sl * BS + b) * OO + t];
        s_lds[t] = scale * s;
    }
    __syncthreads();
    if (t < JJ) {
        float n2 = 0.f;
#pragma unroll
        for (int d = 0; d < DD; ++d) { float v = s_lds[t * DD + d]; n2 += v * v; }
        cf[t] = sqrtf(n2) / (1.0f + n2);   // ||s|| / (1+||s||^2)
    }
    __syncthreads();
    if (t < OO) v_lds[t] = s_lds[t] * cf[t >> 5];
    __syncthreads();

    // ---- delta[j][i] = sum_d v[j,d] * pred[b][j*32+d][i], lane holds 4 i (j = w) ----
    {
        float a0 = 0.f, a1 = 0.f, a2 = 0.f, a3 = 0.f;
        const unsigned short* rp = pred + ((size_t)b * OO + w * DD) * II + ic * 256 + l * 4;
#pragma unroll 8
        for (int d = 0; d < DD; ++d) {
            u16x4 u = *(const u16x4*)(rp + (size_t)d * II);
            float vv = v_lds[w * DD + d];
            a0 += vv * b2f(u[0]); a1 += vv * b2f(u[1]);
            a2 += vv * b2f(u[2]); a3 += vv * b2f(u[3]);
        }
        float4 lg;
        float* bg = blogG + ((size_t)b * JJ + w) * II + ic * 256 + l * 4;
        if (FIRST) {
            lg = make_float4(a0, a1, a2, a3);
            *(float4*)bg = lg;
        } else {
            float4 p = *(const float4*)bg;
            lg = make_float4(p.x + a0, p.y + a1, p.z + a2, p.w + a3);
        }
        *(float4*)&dbuf[w][l * 4] = lg;
    }
    __syncthreads();

    // ---- softmax over j at each i (threads 0..255) ----
    if (t < 256) {
        float lg[JJ];
#pragma unroll
        for (int j = 0; j < JJ; ++j) lg[j] = dbuf[j][t];
        float m = lg[0];
#pragma unroll
        for (int j = 1; j < JJ; ++j) m = fmaxf(m, lg[j]);
        float Z = 0.f, c[JJ];
#pragma unroll
        for (int j = 0; j < JJ; ++j) { c[j] = __expf(lg[j] - m); Z += c[j]; }
        float inv = 1.0f / Z;
#pragma unroll
        for (int j = 0; j < JJ; ++j) dbuf[j][t] = c[j] * inv;
    }
    __syncthreads();

    // ---- wsum partial: psumOut[o] = sum_{i in slice} c[j][i]*pred[b][o][i] (j = w) ----
    {
        float4 c4 = *(const float4*)&dbuf[w][l * 4];
        const unsigned short* rp = pred + ((size_t)b * OO + w * DD) * II + ic * 256 + l * 4;
#pragma unroll 4
        for (int d = 0; d < DD; ++d) {
            u16x4 u = *(const u16x4*)(rp + (size_t)d * II);
            float s = c4.x * b2f(u[0]) + c4.y * b2f(u[1]) + c4.z * b2f(u[2]) + c4.w * b2f(u[3]);
#pragma unroll
            for (int off = 32; off > 0; off >>= 1) s += __shfl_down(s, off);
            if (l == 0) psumOut[((size_t)ic * BS + b) * OO + w * DD + d] = s;
        }
    }
}

// ---------- final: reduce psum2 slices, squash, write f32 out ----------
__global__ __launch_bounds__(320) void k_final2(const float* __restrict__ psum2,
                                                float* __restrict__ out) {
    __shared__ float s_lds[OO];
    __shared__ float cf[JJ];
    int b = blockIdx.x, t = threadIdx.x;
    float s = 0.f;
#pragma unroll
    for (int sl = 0; sl < 4; ++sl) s += psum2[((size_t)sl * BS + b) * OO + t];
    s_lds[t] = s;
    __syncthreads();
    if (t < JJ) {
        float n2 = 0.f;
#pragma unroll
        for (int d = 0; d < DD; ++d) { float v = s_lds[t * DD + d]; n2 += v * v; }
        cf[t] = sqrtf(n2) / (1.0f + n2);
    }
    __syncthreads();
    out[b * OO + t] = s_lds[t] * cf[t >> 5];
}

extern "C" void kernel_launch(void* const* d_in, const int* in_sizes, int n_in,
                              void* d_out, int out_size, void* d_ws, size_t ws_size,
                              hipStream_t stream) {
    const float* x  = (const float*)d_in[0];  // [64][256][1024] f32
    const float* W  = (const float*)d_in[1];  // [320][256] f32
    const float* Wb = (const float*)d_in[2];  // [320] f32

    char* ws = (char*)d_ws;
    unsigned short* pred = (unsigned short*)ws;             // 41,943,040 B
    unsigned short* Wl   = (unsigned short*)(ws + 41943040);// 163,840 B  -> 42,106,880
    float* psum0 = (float*)(ws + 42106880);                 // 655,360 B  -> 42,762,240
    float* psum1 = (float*)(ws + 42762240);                 // 327,680 B  -> 43,089,920
    float* psum2 = (float*)(ws + 43089920);                 // 327,680 B  -> 43,417,600
    float* blogG = (float*)(ws + 43417600);                 // 2,621,440 B-> 46,039,040

    k_prepW<<<40, 256, 0, stream>>>(W, Wl);
    k_gemm3<<<dim3(8, BS), 512, 0, stream>>>(x, Wl, Wb, pred, psum0);
    k_routeP<true><<<dim3(4, BS), 640, 0, stream>>>(psum0, 8, 0.1f, pred, blogG, psum1);
    k_routeP<false><<<dim3(4, BS), 640, 0, stream>>>(psum1, 4, 1.0f, pred, blogG, psum2);
    k_final2<<<BS, 320, 0, stream>>>(psum2, (float*)d_out);
}